// Round 1
// baseline (102.523 us; speedup 1.0000x reference)
//
#include <hip/hip_runtime.h>
#include <cstdint>
#include <cstddef>

// GAT layer: B=4, H=8, N=2048, Din=256, O=64
// out[b,h,i,o] = sum_j softmax_j(leaky_relu(src[i]+dst[j])) * h_[b,h,j,o] + bias[o]
// src = h_ @ a_src, dst = h_ @ a_dst, h_ = h @ w[head]
//
// Key trick: row max of logits is leaky(src_i + max_j dst_j) exactly (monotonicity),
// so no online-softmax rescaling is needed. All logits kept in log2 domain
// (src/dst pre-scaled by log2e) so the inner loop uses exp2 directly.

#define HEADS 8
#define DIN   256
#define HDIM  64
#define NB    4
#define NN    2048

typedef __attribute__((ext_vector_type(8))) short bf16x8;
typedef __attribute__((ext_vector_type(4))) float f32x4;

__device__ __forceinline__ unsigned short f2bf(float f) {
  union { float f; unsigned u; } v; v.f = f;
  unsigned r = v.u + 0x7FFFu + ((v.u >> 16) & 1u);   // RNE
  return (unsigned short)(r >> 16);
}
__device__ __forceinline__ float bf2f(unsigned short u) {
  union { unsigned u; float f; } v; v.u = ((unsigned)u) << 16;
  return v.f;
}

// ---------------- k0: w [H][K][O] f32 -> wt [H][O][K] bf16 ----------------
__global__ __launch_bounds__(256) void gat_wt(const float* __restrict__ w,
                                              unsigned short* __restrict__ wt) {
  const int idx = blockIdx.x * 256 + threadIdx.x;   // over 8*256*64 = 131072
  const int o  = idx & 63;
  const int k  = (idx >> 6) & 255;
  const int hd = idx >> 14;
  wt[(hd * HDIM + o) * DIN + k] = f2bf(w[idx]);
}

// ---------------- k1: h_ projection; writes V^T = h_t[bh][o][n] bf16 ------
// grid (HEADS, 64): head = bx, row-tile(128 rows of B*N=8192) = by
__global__ __launch_bounds__(256) void gat_proj(const float* __restrict__ h,
                                                const unsigned short* __restrict__ wt,
                                                unsigned short* __restrict__ h_t) {
  const int head = blockIdx.x;
  const int rt   = blockIdx.y;
  const int tid  = threadIdx.x;
  const int w    = tid >> 6;
  const int lane = tid & 63;
  const int l15  = lane & 15, lg = lane >> 4;

  const int rowg = rt * 128 + w * 32;                 // global row in [0,8192)
  const float* hb = h + (size_t)rowg * DIN;
  const unsigned short* wb = wt + head * (HDIM * DIN);

  f32x4 acc[2][4] = {};
#pragma unroll
  for (int kk = 0; kk < 8; ++kk) {
    const int k0 = kk * 32 + lg * 8;
    bf16x8 af[2];
#pragma unroll
    for (int m = 0; m < 2; ++m) {
      const float* ap = hb + (size_t)(m * 16 + l15) * DIN + k0;
      float4 x0 = *(const float4*)ap;
      float4 x1 = *(const float4*)(ap + 4);
      af[m][0] = (short)f2bf(x0.x); af[m][1] = (short)f2bf(x0.y);
      af[m][2] = (short)f2bf(x0.z); af[m][3] = (short)f2bf(x0.w);
      af[m][4] = (short)f2bf(x1.x); af[m][5] = (short)f2bf(x1.y);
      af[m][6] = (short)f2bf(x1.z); af[m][7] = (short)f2bf(x1.w);
    }
    bf16x8 bfr[4];
#pragma unroll
    for (int n = 0; n < 4; ++n)
      bfr[n] = *(const bf16x8*)(wb + (size_t)(n * 16 + l15) * DIN + k0);
#pragma unroll
    for (int m = 0; m < 2; ++m)
#pragma unroll
      for (int n = 0; n < 4; ++n)
        acc[m][n] = __builtin_amdgcn_mfma_f32_16x16x32_bf16(af[m], bfr[n], acc[m][n], 0, 0, 0);
  }

  // write transposed: h_t[bh][o][n], C-frag regs are 4 consecutive rows(n) same col(o)
  const int b   = (rt * 128) >> 11;
  const int nl0 = ((rt * 128) & 2047) + w * 32;
  const int bh  = b * HEADS + head;
  unsigned short* hb_t = h_t + (size_t)bh * (HDIM * NN);
#pragma unroll
  for (int m = 0; m < 2; ++m)
#pragma unroll
    for (int n = 0; n < 4; ++n) {
      ushort4 pk;
      pk.x = f2bf(acc[m][n][0]); pk.y = f2bf(acc[m][n][1]);
      pk.z = f2bf(acc[m][n][2]); pk.w = f2bf(acc[m][n][3]);
      const int o  = n * 16 + l15;
      const int nl = nl0 + m * 16 + lg * 4;
      *(ushort4*)(hb_t + (size_t)o * NN + nl) = pk;
    }
}

// ---------------- k2: src/dst logit vectors (pre-scaled by log2e) ---------
__global__ __launch_bounds__(256) void gat_srcdst(const unsigned short* __restrict__ h_t,
                                                  const float* __restrict__ a_src,
                                                  const float* __restrict__ a_dst,
                                                  float* __restrict__ src_s,
                                                  float* __restrict__ dst_s) {
  const int g  = blockIdx.x * 256 + threadIdx.x;    // 0..32767, 2 n's each
  const int bh = g >> 10;
  const int n0 = (g & 1023) * 2;
  const int hd = bh & 7;
  const unsigned short* vb = h_t + (size_t)bh * (HDIM * NN) + n0;
  float ss0 = 0.f, ss1 = 0.f, sd0 = 0.f, sd1 = 0.f;
#pragma unroll 8
  for (int o = 0; o < HDIM; ++o) {
    ushort2 v = *(const ushort2*)(vb + (size_t)o * NN);
    float v0 = bf2f(v.x), v1 = bf2f(v.y);
    float as = a_src[hd * HDIM + o];
    float ad = a_dst[hd * HDIM + o];
    ss0 = fmaf(v0, as, ss0); ss1 = fmaf(v1, as, ss1);
    sd0 = fmaf(v0, ad, sd0); sd1 = fmaf(v1, ad, sd1);
  }
  const float LOG2E = 1.4426950408889634f;
  float2 s{ss0 * LOG2E, ss1 * LOG2E};
  float2 d{sd0 * LOG2E, sd1 * LOG2E};
  *(float2*)(src_s + (size_t)bh * NN + n0) = s;
  *(float2*)(dst_s + (size_t)bh * NN + n0) = d;
}

// ---------------- k3: flash GAT attention ---------------------------------
// grid (16, 32): i-tile = bx (consecutive blocks share bh -> L2 reuse of V), bh = by
__global__ __launch_bounds__(256) void gat_flash(const float* __restrict__ src_s,
                                                 const float* __restrict__ dst_s,
                                                 const unsigned short* __restrict__ h_t,
                                                 const float* __restrict__ bias,
                                                 float* __restrict__ out) {
  const int it  = blockIdx.x;
  const int bh  = blockIdx.y;
  const int tid = threadIdx.x;
  const int w   = tid >> 6;
  const int lane = tid & 63;
  const int l15 = lane & 15, lg = lane >> 4;

  const float* dstp = dst_s + (size_t)bh * NN;
  const float* srcp = src_s + (size_t)bh * NN + it * 128 + w * 32;

  // exact global max of dst for this (b,h)  (row max = leaky(src_i + dmax))
  float dm = -1e30f;
#pragma unroll
  for (int t = 0; t < NN / 256; ++t) dm = fmaxf(dm, dstp[tid + t * 256]);
#pragma unroll
  for (int off = 32; off >= 1; off >>= 1) dm = fmaxf(dm, __shfl_xor(dm, off));
  __shared__ float red[4];
  if (lane == 0) red[w] = dm;
  __syncthreads();
  dm = fmaxf(fmaxf(red[0], red[1]), fmaxf(red[2], red[3]));

  // per-lane row state for A-frag rows (row = l15 within each 16-row m-tile)
  float sm0[2], c0[2];
#pragma unroll
  for (int m = 0; m < 2; ++m) {
    float sv   = srcp[m * 16 + l15];
    float smax = sv + dm;
    float mi   = fmaxf(smax, 0.2f * smax);   // exact row max (log2 domain)
    sm0[m] = sv - mi;                        // pos branch:  p2 = sm0 + d
    c0[m]  = fmaf(0.2f, sv, -mi);            // neg branch:  p2 = 0.2*d + c0
  }

  f32x4 acc[2][4] = {};
  float lsum[2] = {0.f, 0.f};
  const unsigned short* vb = h_t + (size_t)bh * (HDIM * NN);

  for (int jc = 0; jc < NN / 32; ++jc) {
    const int k0 = jc * 32 + lg * 8;
    float4 d0 = *(const float4*)(dstp + k0);
    float4 d1 = *(const float4*)(dstp + k0 + 4);
    float d[8] = {d0.x, d0.y, d0.z, d0.w, d1.x, d1.y, d1.z, d1.w};

    bf16x8 af[2];
#pragma unroll
    for (int m = 0; m < 2; ++m) {
      float pv[8];
#pragma unroll
      for (int jj = 0; jj < 8; ++jj) {
        float a = sm0[m] + d[jj];
        float b = fmaf(0.2f, d[jj], c0[m]);
        float p = exp2f(fmaxf(a, b));        // <= 1 always
        pv[jj] = p;
        af[m][jj] = (short)f2bf(p);
      }
      lsum[m] += ((pv[0] + pv[1]) + (pv[2] + pv[3])) + ((pv[4] + pv[5]) + (pv[6] + pv[7]));
    }

    bf16x8 bfr[4];
#pragma unroll
    for (int n = 0; n < 4; ++n)
      bfr[n] = *(const bf16x8*)(vb + (size_t)(n * 16 + l15) * NN + k0);
#pragma unroll
    for (int m = 0; m < 2; ++m)
#pragma unroll
      for (int n = 0; n < 4; ++n)
        acc[m][n] = __builtin_amdgcn_mfma_f32_16x16x32_bf16(af[m], bfr[n], acc[m][n], 0, 0, 0);
  }

  // finalize: full row sums (lanes {l, l^16, l^32, l^48} hold partials)
  float linv[2];
#pragma unroll
  for (int m = 0; m < 2; ++m) {
    float l = lsum[m];
    l += __shfl_xor(l, 16);
    l += __shfl_xor(l, 32);
    linv[m] = 1.0f / l;
  }
  float bb[4];
#pragma unroll
  for (int n = 0; n < 4; ++n) bb[n] = bias[n * 16 + l15];

  float* ob = out + ((size_t)bh * NN + it * 128 + w * 32) * HDIM;
#pragma unroll
  for (int m = 0; m < 2; ++m) {
#pragma unroll
    for (int reg = 0; reg < 4; ++reg) {
      float lv = __shfl(linv[m], lg * 4 + reg);   // C row = lg*4+reg, l state lives at lane=row
      const int r = m * 16 + lg * 4 + reg;
#pragma unroll
      for (int n = 0; n < 4; ++n)
        ob[(size_t)r * HDIM + n * 16 + l15] = fmaf(acc[m][n][reg], lv, bb[n]);
    }
  }
}

extern "C" void kernel_launch(void* const* d_in, const int* in_sizes, int n_in,
                              void* d_out, int out_size, void* d_ws, size_t ws_size,
                              hipStream_t stream) {
  const float* h     = (const float*)d_in[0];   // [4,2048,256]
  const float* w     = (const float*)d_in[1];   // [8,256,64]
  const float* a_src = (const float*)d_in[2];   // [8,64,1]
  const float* a_dst = (const float*)d_in[3];   // [8,64,1]
  const float* bias  = (const float*)d_in[4];   // [64]
  float* out = (float*)d_out;                   // [4,8,2048,64]

  // ws layout (needs ~8.75 MB):
  char* ws = (char*)d_ws;
  unsigned short* wt  = (unsigned short*)ws;                       // 256 KB
  unsigned short* h_t = (unsigned short*)(ws + 262144);            // 8 MB  (V^T bf16)
  float* src_s = (float*)(ws + 262144 + 8388608);                  // 256 KB
  float* dst_s = (float*)(ws + 262144 + 8388608 + 262144);         // 256 KB

  hipLaunchKernelGGL(gat_wt,     dim3(512),     dim3(256), 0, stream, w, wt);
  hipLaunchKernelGGL(gat_proj,   dim3(8, 64),   dim3(256), 0, stream, h, wt, h_t);
  hipLaunchKernelGGL(gat_srcdst, dim3(128),     dim3(256), 0, stream, h_t, a_src, a_dst, src_s, dst_s);
  hipLaunchKernelGGL(gat_flash,  dim3(16, 32),  dim3(256), 0, stream, src_s, dst_s, h_t, bias, out);
}